// Round 5
// baseline (631.271 us; speedup 1.0000x reference)
//
#include <hip/hip_runtime.h>
#include <stdint.h>

#define NN 100000
#define NE 1600000
#define CH 128
#define OC 64
#define NG 512
#define NBLK 256      // partition blocks
#define NBMAX 4096    // max coarse buckets (nodes/256)
#define PADSLACK 2048 // per-bucket ssrc slack: 256 nodes * 8 (self + pad to x8)

typedef unsigned int uint;
typedef unsigned short ushort;
typedef __attribute__((ext_vector_type(8))) short short8;
typedef __attribute__((ext_vector_type(4))) float floatx4;

__device__ __forceinline__ ushort f2bf(float f) {
    uint u = __float_as_uint(f);
    uint r = u + 0x7fffu + ((u >> 16) & 1u);  // round-to-nearest-even
    return (ushort)(r >> 16);
}
__device__ __forceinline__ float bf_lo(uint g) { return __uint_as_float(g << 16); }
__device__ __forceinline__ float bf_hi(uint g) { return __uint_as_float(g & 0xffff0000u); }

__device__ __forceinline__ void acc8(uint4 g, float& a0, float& a1, float& a2, float& a3,
                                     float& a4, float& a5, float& a6, float& a7) {
    a0 += bf_lo(g.x); a1 += bf_hi(g.x);
    a2 += bf_lo(g.y); a3 += bf_hi(g.y);
    a4 += bf_lo(g.z); a5 += bf_hi(g.z);
    a6 += bf_lo(g.w); a7 += bf_hi(g.w);
}

// ---------------- bucket histogram, written bucket-major ----------------
__global__ __launch_bounds__(256) void k_hist(const int* __restrict__ dst,
                                              int* __restrict__ bhT,
                                              int E, int NB, int chunk) {
    __shared__ int h[NBMAX];
    int blk = blockIdx.x, tid = threadIdx.x;
    for (int j = tid; j < NB; j += 256) h[j] = 0;
    __syncthreads();
    int lo = blk * chunk, hi = min(E, lo + chunk);
    for (int i = lo + tid; i < hi; i += 256) atomicAdd(&h[dst[i] >> 8], 1);
    __syncthreads();
    for (int j = tid; j < NB; j += 256) bhT[j * NBLK + blk] = h[j];
}

// ---------------- prefix scan (2-phase; block offsets folded by consumers) ---
__global__ __launch_bounds__(256) void k_scan1(const int* __restrict__ in,
                                               int* __restrict__ excl,
                                               int* __restrict__ bsums, int T) {
    __shared__ int sd[256];
    int tid = threadIdx.x;
    int base = blockIdx.x * 1024 + tid * 4;
    int v[4];
#pragma unroll
    for (int i = 0; i < 4; i++) v[i] = (base + i < T) ? in[base + i] : 0;
    int tsum = v[0] + v[1] + v[2] + v[3];
    int val = tsum;
    sd[tid] = val; __syncthreads();
    for (int off = 1; off < 256; off <<= 1) {
        int t = (tid >= off) ? sd[tid - off] : 0;
        __syncthreads();
        val += t; sd[tid] = val;
        __syncthreads();
    }
    int run = val - tsum;
#pragma unroll
    for (int i = 0; i < 4; i++) {
        if (base + i < T) excl[base + i] = run;
        run += v[i];
    }
    if (tid == 255) bsums[blockIdx.x] = val;
}

__global__ __launch_bounds__(128) void k_scan2(int* __restrict__ bs, int nb) {
    __shared__ int sd[128];
    int tid = threadIdx.x;
    int v = (tid < nb) ? bs[tid] : 0;
    int val = v;
    sd[tid] = val; __syncthreads();
    for (int off = 1; off < 128; off <<= 1) {
        int t = (tid >= off) ? sd[tid - off] : 0;
        __syncthreads();
        val += t; sd[tid] = val;
        __syncthreads();
    }
    if (tid < nb) bs[tid] = val - v;
}

// ------- partition: packed (src<<8)|(dst&255) into per-(bucket,block) segs ----
__global__ __launch_bounds__(256) void k_part(const int* __restrict__ src,
                                              const int* __restrict__ dst,
                                              const int* __restrict__ off,
                                              const int* __restrict__ boff,
                                              int* __restrict__ ebuf,
                                              int E, int NB, int chunk) {
    __shared__ int cur[NBMAX];
    int blk = blockIdx.x, tid = threadIdx.x;
    for (int j = tid; j < NB; j += 256) {
        int idx = j * NBLK + blk;
        cur[j] = off[idx] + boff[idx >> 10];
    }
    __syncthreads();
    int lo = blk * chunk, hi = min(E, lo + chunk);
    for (int i = lo + tid; i < hi; i += 256) {
        int s = src[i], d = dst[i];
        int pos = atomicAdd(&cur[d >> 8], 1);
        ebuf[pos] = (s << 8) | (d & 255);
    }
}

// ------- CSR finalize per bucket: deg, dinv, (start,end), padded scatter -----
// Row layout: [deg real edges][self node][pad to x8 with sentinel n].
// Emits s32[node][32]: first 32 slots at fixed stride -> straight-line aggs.
__global__ __launch_bounds__(256) void k_csr(const int* __restrict__ ebuf,
                                             const int* __restrict__ off,
                                             const int* __restrict__ boff,
                                             int2* __restrict__ rowse,
                                             float* __restrict__ dinv,
                                             int* __restrict__ ssrc,
                                             int* __restrict__ s32,
                                             int n, int NB, int E) {
    __shared__ int cnt[256], sc[256], cur[256];
    int b = blockIdx.x, tid = threadIdx.x;
    int node0 = b << 8;
    int i0 = b * NBLK;
    int bstart = off[i0] + boff[i0 >> 10];
    int bend = E;
    if (b + 1 < NB) {
        int i1 = (b + 1) * NBLK;
        bend = off[i1] + boff[i1 >> 10];
    }
    // padded ssrc region for this bucket
    int rbeg = bstart + b * PADSLACK;
    int rend = bend + (b + 1) * PADSLACK;
    cnt[tid] = 0;
    __syncthreads();
    for (int i = bstart + tid; i < bend; i += 256)
        atomicAdd(&cnt[ebuf[i] & 255], 1);
    // init whole padded region to sentinel (real edges overwrite below)
    for (int i = rbeg + tid; i < rend; i += 256) ssrc[i] = n;
    __syncthreads();
    int v = cnt[tid];
    int pv = (v + 8) & ~7;        // +1 self slot, padded to multiple of 8
    int val = pv;
    sc[tid] = val; __syncthreads();
    for (int o = 1; o < 256; o <<= 1) {
        int t = (tid >= o) ? sc[tid - o] : 0;
        __syncthreads();
        val += t; sc[tid] = val;
        __syncthreads();
    }
    int excl = val - pv;
    int base = rbeg + excl;
    int node = node0 + tid;
    if (node < n) {
        rowse[node] = make_int2(base, base + pv);
        dinv[node] = rsqrtf((float)v + 1.0f);
    }
    cur[tid] = base;
    __syncthreads();
    for (int i = bstart + tid; i < bend; i += 256) {
        int e = ebuf[i];
        int pos = atomicAdd(&cur[e & 255], 1);
        ssrc[pos] = e >> 8;        // s < 2^23, sign-safe
    }
    __syncthreads();
    // self slot + fixed-stride first-32 table
    if (node < n) {
        ssrc[base + v] = node;    // self-loop (own write, read below by owner)
        int kk[32];
#pragma unroll
        for (int k = 0; k < 32; k++) kk[k] = (k < pv) ? ssrc[base + k] : n;
        int4* d4 = (int4*)(s32 + ((size_t)node << 5));
        d4[0] = make_int4(kk[0], kk[1], kk[2], kk[3]);
        d4[1] = make_int4(kk[4], kk[5], kk[6], kk[7]);
        d4[2] = make_int4(kk[8], kk[9], kk[10], kk[11]);
        d4[3] = make_int4(kk[12], kk[13], kk[14], kk[15]);
        d4[4] = make_int4(kk[16], kk[17], kk[18], kk[19]);
        d4[5] = make_int4(kk[20], kk[21], kk[22], kk[23]);
        d4[6] = make_int4(kk[24], kk[25], kk[26], kk[27]);
        d4[7] = make_int4(kk[28], kk[29], kk[30], kk[31]);
    }
}

// --- fused cvt + prep: blocks [0,cvtBlocks) do fp32->bf16 with dinv scale;
// --- remaining blocks: weight prep, sentinel rows, q/cnt zeroing.
__global__ __launch_bounds__(256) void k_cvtprep(const float* __restrict__ x,
                                                 const float* __restrict__ dinv,
                                                 ushort* __restrict__ xb,
                                                 const float* __restrict__ W1,
                                                 const float* __restrict__ W2,
                                                 const float* __restrict__ b2,
                                                 const float* __restrict__ Wfc,
                                                 const float* __restrict__ bfc,
                                                 ushort* __restrict__ Wt,
                                                 ushort* __restrict__ Wct,
                                                 float* __restrict__ bc,
                                                 ushort* __restrict__ tb,
                                                 float* __restrict__ q,
                                                 float* __restrict__ cnt,
                                                 int n, int cvtBlocks) {
    if ((int)blockIdx.x < cvtBlocks) {
        int i = (blockIdx.x * 256 + threadIdx.x) * 4;
        if (i >= n * CH) return;
        float d = dinv[i >> 7];
        float4 v = *(const float4*)(x + i);
        uint2 o;
        o.x = (uint)f2bf(v.x * d) | ((uint)f2bf(v.y * d) << 16);
        o.y = (uint)f2bf(v.z * d) | ((uint)f2bf(v.w * d) << 16);
        *(uint2*)(xb + i) = o;
        return;
    }
    const int T0 = CH * CH;
    const int T1 = T0 + CH * OC;
    const int T2 = T1 + OC;
    const int T3 = T2 + CH;
    const int T4 = T3 + OC;
    const int T5 = T4 + NG * OC;
    const int T6 = T5 + NG;
    int t = ((int)blockIdx.x - cvtBlocks) * 256 + threadIdx.x;
    if (t < T0) {
        int nc = t >> 7, k = t & 127;
        Wt[nc * CH + k] = f2bf(W1[k * CH + nc]);
    } else if (t < T1) {
        int u = t - T0;
        int k = u >> 6, o = u & 63;
        float acc = 0.f;
        for (int j = 0; j < CH; j++) acc += W2[k * CH + j] * Wfc[j * OC + o];
        Wct[o * CH + k] = f2bf(acc);   // [OC][CH] bf16, MFMA B-operand layout
    } else if (t < T2) {
        int o = t - T1;
        float acc = bfc[o];
        for (int j = 0; j < CH; j++) acc += b2[j] * Wfc[j * OC + o];
        bc[o] = acc;
    } else if (t < T3) {
        xb[(size_t)n * CH + (t - T2)] = 0;   // sentinel row, 128ch
    } else if (t < T4) {
        tb[(size_t)n * OC + (t - T3)] = 0;   // sentinel row, 64ch
    } else if (t < T5) {
        q[t - T4] = 0.f;                     // pool accumulators
    } else if (t < T6) {
        cnt[t - T5] = 0.f;                   // pool counts
    }
}

// ------- aggregation (128 ch): two straight-line phases via s32 ------------
// out = dinv_dst * sum(slots); slots include self; sentinel rows are zeros.
__global__ __launch_bounds__(256) void k_agg(const ushort* __restrict__ Hs,
                                             const int2* __restrict__ rowse,
                                             const int* __restrict__ ssrc,
                                             const int* __restrict__ s32,
                                             const float* __restrict__ dinv,
                                             ushort* __restrict__ out, int n) {
    int wid = (blockIdx.x << 2) | (threadIdx.x >> 6);
    if (wid >= n) return;
    int uw = __builtin_amdgcn_readfirstlane(wid);
    int lane = threadIdx.x & 63;
    int sub = lane >> 4;          // 4 slot groups
    int li = lane & 15;
    int c = li * 8;               // 8 bf16 channels = 16 B per lane
    const int* srow = s32 + ((size_t)uw << 5);
    int4 sa = *(const int4*)(srow + sub * 4);        // slots 0..15
    int4 sb = *(const int4*)(srow + 16 + sub * 4);   // slots 16..31
    int2 se = rowse[uw];
    int pv = se.y - se.x;
    float a0 = 0.f, a1 = 0.f, a2 = 0.f, a3 = 0.f;
    float a4 = 0.f, a5 = 0.f, a6 = 0.f, a7 = 0.f;
    {   // phase A
        uint4 g0 = *(const uint4*)(Hs + (sa.x << 7) + c);
        uint4 g1 = *(const uint4*)(Hs + (sa.y << 7) + c);
        uint4 g2 = *(const uint4*)(Hs + (sa.z << 7) + c);
        uint4 g3 = *(const uint4*)(Hs + (sa.w << 7) + c);
        acc8(g0, a0, a1, a2, a3, a4, a5, a6, a7);
        acc8(g1, a0, a1, a2, a3, a4, a5, a6, a7);
        acc8(g2, a0, a1, a2, a3, a4, a5, a6, a7);
        acc8(g3, a0, a1, a2, a3, a4, a5, a6, a7);
    }
    if (pv > 16) {   // phase B (wave-uniform branch)
        uint4 g0 = *(const uint4*)(Hs + (sb.x << 7) + c);
        uint4 g1 = *(const uint4*)(Hs + (sb.y << 7) + c);
        uint4 g2 = *(const uint4*)(Hs + (sb.z << 7) + c);
        uint4 g3 = *(const uint4*)(Hs + (sb.w << 7) + c);
        acc8(g0, a0, a1, a2, a3, a4, a5, a6, a7);
        acc8(g1, a0, a1, a2, a3, a4, a5, a6, a7);
        acc8(g2, a0, a1, a2, a3, a4, a5, a6, a7);
        acc8(g3, a0, a1, a2, a3, a4, a5, a6, a7);
        if (pv > 32) {   // rare heavy nodes
            int e = se.x + 32, e1 = se.y;
            for (; e + 16 <= e1; e += 16) {
                int s0 = ssrc[e + sub];
                int s1 = ssrc[e + 4 + sub];
                int s2 = ssrc[e + 8 + sub];
                int s3 = ssrc[e + 12 + sub];
                uint4 g0 = *(const uint4*)(Hs + (s0 << 7) + c);
                uint4 g1 = *(const uint4*)(Hs + (s1 << 7) + c);
                uint4 g2 = *(const uint4*)(Hs + (s2 << 7) + c);
                uint4 g3 = *(const uint4*)(Hs + (s3 << 7) + c);
                acc8(g0, a0, a1, a2, a3, a4, a5, a6, a7);
                acc8(g1, a0, a1, a2, a3, a4, a5, a6, a7);
                acc8(g2, a0, a1, a2, a3, a4, a5, a6, a7);
                acc8(g3, a0, a1, a2, a3, a4, a5, a6, a7);
            }
            if (e < e1) {   // exactly 8 remaining
                int s0 = ssrc[e + sub];
                int s1 = ssrc[e + 4 + sub];
                uint4 g0 = *(const uint4*)(Hs + (s0 << 7) + c);
                uint4 g1 = *(const uint4*)(Hs + (s1 << 7) + c);
                acc8(g0, a0, a1, a2, a3, a4, a5, a6, a7);
                acc8(g1, a0, a1, a2, a3, a4, a5, a6, a7);
            }
        }
    }
    a0 += __shfl_xor(a0, 16); a0 += __shfl_xor(a0, 32);
    a1 += __shfl_xor(a1, 16); a1 += __shfl_xor(a1, 32);
    a2 += __shfl_xor(a2, 16); a2 += __shfl_xor(a2, 32);
    a3 += __shfl_xor(a3, 16); a3 += __shfl_xor(a3, 32);
    a4 += __shfl_xor(a4, 16); a4 += __shfl_xor(a4, 32);
    a5 += __shfl_xor(a5, 16); a5 += __shfl_xor(a5, 32);
    a6 += __shfl_xor(a6, 16); a6 += __shfl_xor(a6, 32);
    a7 += __shfl_xor(a7, 16); a7 += __shfl_xor(a7, 32);
    if (sub == 0) {
        float d = dinv[uw];
        uint4 o;
        o.x = (uint)f2bf(a0 * d) | ((uint)f2bf(a1 * d) << 16);
        o.y = (uint)f2bf(a2 * d) | ((uint)f2bf(a3 * d) << 16);
        o.z = (uint)f2bf(a4 * d) | ((uint)f2bf(a5 * d) << 16);
        o.w = (uint)f2bf(a6 * d) | ((uint)f2bf(a7 * d) << 16);
        *(uint4*)(out + ((size_t)uw << 7) + c) = o;
    }
}

// ------- aggregation (64 ch) + fused mean-pool accumulation -----------------
// z = dinv_dst * sum(slots); atomicAdd fp32 partials into q[g][64], cnt[g].
__global__ __launch_bounds__(256) void k_agg64p(const ushort* __restrict__ Hs,
                                                const int2* __restrict__ rowse,
                                                const int* __restrict__ ssrc,
                                                const int* __restrict__ s32,
                                                const float* __restrict__ dinv,
                                                const int* __restrict__ batch,
                                                float* __restrict__ q,
                                                float* __restrict__ cnt, int n) {
    int wid = (blockIdx.x << 2) | (threadIdx.x >> 6);
    if (wid >= n) return;
    int uw = __builtin_amdgcn_readfirstlane(wid);
    int lane = threadIdx.x & 63;
    int sub = lane >> 3;          // 8 slot groups
    int li = lane & 7;
    int c = li * 8;               // 8 bf16 channels = 16 B per lane
    const int* srow = s32 + ((size_t)uw << 5);
    int2 sa = *(const int2*)(srow + sub * 2);        // slots 0..15
    int2 sb = *(const int2*)(srow + 16 + sub * 2);   // slots 16..31
    int2 se = rowse[uw];
    int pv = se.y - se.x;
    float a0 = 0.f, a1 = 0.f, a2 = 0.f, a3 = 0.f;
    float a4 = 0.f, a5 = 0.f, a6 = 0.f, a7 = 0.f;
    {   // phase A
        uint4 g0 = *(const uint4*)(Hs + (sa.x << 6) + c);
        uint4 g1 = *(const uint4*)(Hs + (sa.y << 6) + c);
        acc8(g0, a0, a1, a2, a3, a4, a5, a6, a7);
        acc8(g1, a0, a1, a2, a3, a4, a5, a6, a7);
    }
    if (pv > 16) {   // phase B
        uint4 g0 = *(const uint4*)(Hs + (sb.x << 6) + c);
        uint4 g1 = *(const uint4*)(Hs + (sb.y << 6) + c);
        acc8(g0, a0, a1, a2, a3, a4, a5, a6, a7);
        acc8(g1, a0, a1, a2, a3, a4, a5, a6, a7);
        if (pv > 32) {   // rare heavy nodes
            int e = se.x + 32, e1 = se.y;
            for (; e + 16 <= e1; e += 16) {
                int s0 = ssrc[e + sub];
                int s1 = ssrc[e + 8 + sub];
                uint4 g0 = *(const uint4*)(Hs + (s0 << 6) + c);
                uint4 g1 = *(const uint4*)(Hs + (s1 << 6) + c);
                acc8(g0, a0, a1, a2, a3, a4, a5, a6, a7);
                acc8(g1, a0, a1, a2, a3, a4, a5, a6, a7);
            }
            if (e < e1) {   // exactly 8 remaining
                int s0 = ssrc[e + sub];
                uint4 g0 = *(const uint4*)(Hs + (s0 << 6) + c);
                acc8(g0, a0, a1, a2, a3, a4, a5, a6, a7);
            }
        }
    }
    a0 += __shfl_xor(a0, 8); a0 += __shfl_xor(a0, 16); a0 += __shfl_xor(a0, 32);
    a1 += __shfl_xor(a1, 8); a1 += __shfl_xor(a1, 16); a1 += __shfl_xor(a1, 32);
    a2 += __shfl_xor(a2, 8); a2 += __shfl_xor(a2, 16); a2 += __shfl_xor(a2, 32);
    a3 += __shfl_xor(a3, 8); a3 += __shfl_xor(a3, 16); a3 += __shfl_xor(a3, 32);
    a4 += __shfl_xor(a4, 8); a4 += __shfl_xor(a4, 16); a4 += __shfl_xor(a4, 32);
    a5 += __shfl_xor(a5, 8); a5 += __shfl_xor(a5, 16); a5 += __shfl_xor(a5, 32);
    a6 += __shfl_xor(a6, 8); a6 += __shfl_xor(a6, 16); a6 += __shfl_xor(a6, 32);
    a7 += __shfl_xor(a7, 8); a7 += __shfl_xor(a7, 16); a7 += __shfl_xor(a7, 32);
    if (sub == 0) {
        float d = dinv[uw];
        int g = batch[uw];
        float* qg = q + g * OC + c;
        atomicAdd(qg + 0, a0 * d);
        atomicAdd(qg + 1, a1 * d);
        atomicAdd(qg + 2, a2 * d);
        atomicAdd(qg + 3, a3 * d);
        atomicAdd(qg + 4, a4 * d);
        atomicAdd(qg + 5, a5 * d);
        atomicAdd(qg + 6, a6 * d);
        atomicAdd(qg + 7, a7 * d);
        if (lane == 0) atomicAdd(&cnt[g], 1.0f);
    }
}

// ---- T = (dinv*relu(Y*W1 + b1)) * Wct : two MFMA stages, LDS tile reuse ----
__global__ __launch_bounds__(256) void k_gemm_mfma(const ushort* __restrict__ Y,
                                                   const ushort* __restrict__ Wt,
                                                   const float* __restrict__ bias,
                                                   const float* __restrict__ dinv,
                                                   const ushort* __restrict__ Wct,
                                                   ushort* __restrict__ T, int n) {
    __shared__ __align__(16) ushort As[128][136];
    int tid = threadIdx.x;
    int r0 = blockIdx.x * 128;
#pragma unroll
    for (int i = 0; i < 8; i++) {
        int idx = tid + i * 256;
        int row = idx >> 4;
        int c8 = (idx & 15) * 8;
        int r = r0 + row;
        uint4 v = make_uint4(0u, 0u, 0u, 0u);
        if (r < n) v = *(const uint4*)(Y + (size_t)r * CH + c8);
        *(uint4*)&As[row][c8] = v;
    }
    __syncthreads();
    int w = tid >> 6, lane = tid & 63;
    int qm = lane & 15, quad = lane >> 4;
    floatx4 acc[2][8];
#pragma unroll
    for (int mi = 0; mi < 2; mi++)
#pragma unroll
        for (int nt = 0; nt < 8; nt++) acc[mi][nt] = (floatx4){0.f, 0.f, 0.f, 0.f};
#pragma unroll
    for (int ks = 0; ks < 4; ks++) {
        int k0 = ks * 32 + quad * 8;
        short8 va0 = *(const short8*)&As[w * 32 + qm][k0];
        short8 va1 = *(const short8*)&As[w * 32 + 16 + qm][k0];
#pragma unroll
        for (int nt = 0; nt < 8; nt++) {
            short8 b = *(const short8*)(Wt + (nt * 16 + qm) * CH + k0);
            acc[0][nt] = __builtin_amdgcn_mfma_f32_16x16x32_bf16(va0, b, acc[0][nt], 0, 0, 0);
            acc[1][nt] = __builtin_amdgcn_mfma_f32_16x16x32_bf16(va1, b, acc[1][nt], 0, 0, 0);
        }
    }
    // epilogue stage 1: hs = dinv*relu(acc+bias), write bf16 back to own rows
#pragma unroll
    for (int mi = 0; mi < 2; mi++) {
#pragma unroll
        for (int reg = 0; reg < 4; reg++) {
            int lrow = w * 32 + mi * 16 + quad * 4 + reg;
            int r = r0 + lrow;
            float d = (r < n) ? dinv[r] : 0.f;   // pad rows -> exact 0
#pragma unroll
            for (int nt = 0; nt < 8; nt++) {
                int cidx = nt * 16 + qm;
                float val = fmaxf(acc[mi][nt][reg] + bias[cidx], 0.f) * d;
                As[lrow][cidx] = f2bf(val);
            }
        }
    }
    __syncthreads();
    // stage 2: T tile = hs(128x128) * Wct(64x128)^T
    floatx4 acc2[2][4];
#pragma unroll
    for (int mi = 0; mi < 2; mi++)
#pragma unroll
        for (int nt = 0; nt < 4; nt++) acc2[mi][nt] = (floatx4){0.f, 0.f, 0.f, 0.f};
#pragma unroll
    for (int ks = 0; ks < 4; ks++) {
        int k0 = ks * 32 + quad * 8;
        short8 va0 = *(const short8*)&As[w * 32 + qm][k0];
        short8 va1 = *(const short8*)&As[w * 32 + 16 + qm][k0];
#pragma unroll
        for (int nt = 0; nt < 4; nt++) {
            short8 b = *(const short8*)(Wct + (nt * 16 + qm) * CH + k0);
            acc2[0][nt] = __builtin_amdgcn_mfma_f32_16x16x32_bf16(va0, b, acc2[0][nt], 0, 0, 0);
            acc2[1][nt] = __builtin_amdgcn_mfma_f32_16x16x32_bf16(va1, b, acc2[1][nt], 0, 0, 0);
        }
    }
#pragma unroll
    for (int mi = 0; mi < 2; mi++) {
#pragma unroll
        for (int reg = 0; reg < 4; reg++) {
            int r = r0 + w * 32 + mi * 16 + quad * 4 + reg;
            if (r >= n) continue;
#pragma unroll
            for (int nt = 0; nt < 4; nt++)
                T[(size_t)r * OC + nt * 16 + qm] = f2bf(acc2[mi][nt][reg]);
        }
    }
}

// ---------------- out = q/cnt + bc ----------------
__global__ __launch_bounds__(256) void k_out(const float* __restrict__ q,
                                             const float* __restrict__ cnt,
                                             const float* __restrict__ bc,
                                             float* __restrict__ out) {
    int t = blockIdx.x * 256 + threadIdx.x;
    int g = t >> 6, o = t & 63;
    out[t] = q[t] / fmaxf(cnt[g], 1.f) + bc[o];
}

extern "C" void kernel_launch(void* const* d_in, const int* in_sizes, int n_in,
                              void* d_out, int out_size, void* d_ws, size_t ws_size,
                              hipStream_t stream) {
    const float* x   = (const float*)d_in[0];
    const float* W1  = (const float*)d_in[1];
    const float* b1  = (const float*)d_in[2];
    const float* W2  = (const float*)d_in[3];
    const float* b2  = (const float*)d_in[4];
    const float* Wfc = (const float*)d_in[5];
    const float* bfc = (const float*)d_in[6];
    const int* edges = (const int*)d_in[7];
    const int* batch = (const int*)d_in[8];

    const int n = in_sizes[8];        // 100000
    const int E = in_sizes[7] / 2;    // 1600000
    const int* esrc = edges;
    const int* edst = edges + E;

    const int NB = (n + 255) >> 8;            // 391 coarse buckets
    const int T = NB * NBLK;
    const int chunk = (E + NBLK - 1) / NBLK;

    char* p = (char*)d_ws;
    auto carve = [&](size_t bytes) {
        void* r = (void*)p;
        p += (bytes + 255) & ~(size_t)255;
        return r;
    };
    int*    bhT       = (int*)carve((size_t)T * 4);
    int*    off       = (int*)carve((size_t)T * 4);
    int*    bsums     = (int*)carve(512);
    int*    ebuf      = (int*)carve((size_t)E * 4);
    int2*   rowse     = (int2*)carve((size_t)n * 8);
    float*  dinv      = (float*)carve((size_t)n * 4);
    int*    ssrc      = (int*)carve(((size_t)E + (size_t)NB * PADSLACK + 256) * 4);
    int*    s32       = (int*)carve((size_t)n * 32 * 4);
    ushort* xb        = (ushort*)carve((size_t)(n + 1) * CH * 2);  // +sentinel row
    ushort* yb        = (ushort*)carve((size_t)n * CH * 2);
    ushort* tb        = (ushort*)carve((size_t)(n + 1) * OC * 2);  // +sentinel row
    ushort* Wt        = (ushort*)carve((size_t)CH * CH * 2);
    ushort* Wct       = (ushort*)carve((size_t)OC * CH * 2);
    float*  bc        = (float*)carve((size_t)OC * 4);
    float*  q         = (float*)carve((size_t)NG * OC * 4);
    float*  cnt       = (float*)carve((size_t)NG * 4);

    int nScanBlocks = (T + 1023) / 1024;
    int cvtBlocks = (n * CH / 4 + 255) / 256;
    int prepBlocks = (CH * CH + CH * OC + OC + CH + OC + NG * OC + NG + 255) / 256;

    // CSR build (atomic-free global ordering; rows = edges+self padded to x8)
    k_hist<<<NBLK, 256, 0, stream>>>(edst, bhT, E, NB, chunk);
    k_scan1<<<nScanBlocks, 256, 0, stream>>>(bhT, off, bsums, T);
    k_scan2<<<1, 128, 0, stream>>>(bsums, nScanBlocks);
    k_part<<<NBLK, 256, 0, stream>>>(esrc, edst, off, bsums, ebuf, E, NB, chunk);
    k_csr<<<NB, 256, 0, stream>>>(ebuf, off, bsums, rowse, dinv, ssrc, s32, n, NB, E);

    // fused features + weight prep + sentinel rows + q/cnt zero
    k_cvtprep<<<cvtBlocks + prepBlocks, 256, 0, stream>>>(
        x, dinv, xb, W1, W2, b2, Wfc, bfc, Wt, Wct, bc, tb, q, cnt, n, cvtBlocks);
    // y = dinv*(sum slots incl self)   (xb -> yb, 128 ch)
    k_agg<<<(n + 3) / 4, 256, 0, stream>>>(xb, rowse, ssrc, s32, dinv, yb, n);
    // t = (dinv*relu(y*W1 + b1)) * Wct   (yb -> tb, 64 ch)
    k_gemm_mfma<<<(n + 127) / 128, 256, 0, stream>>>(yb, Wt, b1, dinv, Wct, tb, n);
    // z-row + pooled accumulation (tb -> q, cnt)
    k_agg64p<<<(n + 3) / 4, 256, 0, stream>>>(tb, rowse, ssrc, s32, dinv, batch, q, cnt, n);
    // out = q/cnt + bc
    k_out<<<(NG * OC + 255) / 256, 256, 0, stream>>>(q, cnt, bc, (float*)d_out);
}

// Round 6
// 312.375 us; speedup vs baseline: 2.0209x; 2.0209x over previous
//
#include <hip/hip_runtime.h>
#include <stdint.h>

#define NN 100000
#define NE 1600000
#define CH 128
#define OC 64
#define NG 512
#define NBLK 256      // partition blocks
#define NBMAX 4096    // max coarse buckets (nodes/256)
#define PADSLACK 2048 // per-bucket ssrc slack: 256 nodes * 8 (self + pad to x8)

typedef unsigned int uint;
typedef unsigned short ushort;
typedef __attribute__((ext_vector_type(8))) short short8;
typedef __attribute__((ext_vector_type(4))) float floatx4;

__device__ __forceinline__ ushort f2bf(float f) {
    uint u = __float_as_uint(f);
    uint r = u + 0x7fffu + ((u >> 16) & 1u);  // round-to-nearest-even
    return (ushort)(r >> 16);
}
__device__ __forceinline__ float bf_lo(uint g) { return __uint_as_float(g << 16); }
__device__ __forceinline__ float bf_hi(uint g) { return __uint_as_float(g & 0xffff0000u); }

__device__ __forceinline__ void acc8(uint4 g, float& a0, float& a1, float& a2, float& a3,
                                     float& a4, float& a5, float& a6, float& a7) {
    a0 += bf_lo(g.x); a1 += bf_hi(g.x);
    a2 += bf_lo(g.y); a3 += bf_hi(g.y);
    a4 += bf_lo(g.z); a5 += bf_hi(g.z);
    a6 += bf_lo(g.w); a7 += bf_hi(g.w);
}

// ---------------- bucket histogram, written bucket-major ----------------
__global__ __launch_bounds__(256) void k_hist(const int* __restrict__ dst,
                                              int* __restrict__ bhT,
                                              int E, int NB, int chunk) {
    __shared__ int h[NBMAX];
    int blk = blockIdx.x, tid = threadIdx.x;
    for (int j = tid; j < NB; j += 256) h[j] = 0;
    __syncthreads();
    int lo = blk * chunk, hi = min(E, lo + chunk);
    for (int i = lo + tid; i < hi; i += 256) atomicAdd(&h[dst[i] >> 8], 1);
    __syncthreads();
    for (int j = tid; j < NB; j += 256) bhT[j * NBLK + blk] = h[j];
}

// ---------------- prefix scan (2-phase; block offsets folded by consumers) ---
__global__ __launch_bounds__(256) void k_scan1(const int* __restrict__ in,
                                               int* __restrict__ excl,
                                               int* __restrict__ bsums, int T) {
    __shared__ int sd[256];
    int tid = threadIdx.x;
    int base = blockIdx.x * 1024 + tid * 4;
    int v[4];
#pragma unroll
    for (int i = 0; i < 4; i++) v[i] = (base + i < T) ? in[base + i] : 0;
    int tsum = v[0] + v[1] + v[2] + v[3];
    int val = tsum;
    sd[tid] = val; __syncthreads();
    for (int off = 1; off < 256; off <<= 1) {
        int t = (tid >= off) ? sd[tid - off] : 0;
        __syncthreads();
        val += t; sd[tid] = val;
        __syncthreads();
    }
    int run = val - tsum;
#pragma unroll
    for (int i = 0; i < 4; i++) {
        if (base + i < T) excl[base + i] = run;
        run += v[i];
    }
    if (tid == 255) bsums[blockIdx.x] = val;
}

__global__ __launch_bounds__(128) void k_scan2(int* __restrict__ bs, int nb) {
    __shared__ int sd[128];
    int tid = threadIdx.x;
    int v = (tid < nb) ? bs[tid] : 0;
    int val = v;
    sd[tid] = val; __syncthreads();
    for (int off = 1; off < 128; off <<= 1) {
        int t = (tid >= off) ? sd[tid - off] : 0;
        __syncthreads();
        val += t; sd[tid] = val;
        __syncthreads();
    }
    if (tid < nb) bs[tid] = val - v;
}

// ------- partition: packed (src<<8)|(dst&255) into per-(bucket,block) segs ----
__global__ __launch_bounds__(256) void k_part(const int* __restrict__ src,
                                              const int* __restrict__ dst,
                                              const int* __restrict__ off,
                                              const int* __restrict__ boff,
                                              int* __restrict__ ebuf,
                                              int E, int NB, int chunk) {
    __shared__ int cur[NBMAX];
    int blk = blockIdx.x, tid = threadIdx.x;
    for (int j = tid; j < NB; j += 256) {
        int idx = j * NBLK + blk;
        cur[j] = off[idx] + boff[idx >> 10];
    }
    __syncthreads();
    int lo = blk * chunk, hi = min(E, lo + chunk);
    for (int i = lo + tid; i < hi; i += 256) {
        int s = src[i], d = dst[i];
        int pos = atomicAdd(&cur[d >> 8], 1);
        ebuf[pos] = (s << 8) | (d & 255);
    }
}

// ------- CSR finalize per bucket: deg, dinv, (start,end), padded scatter -----
// Row layout: [deg real edges][self node][pad to x8 with sentinel n].
// Emits s32[node][32]: first 32 slots at fixed stride -> straight-line aggs.
__global__ __launch_bounds__(256) void k_csr(const int* __restrict__ ebuf,
                                             const int* __restrict__ off,
                                             const int* __restrict__ boff,
                                             int2* __restrict__ rowse,
                                             float* __restrict__ dinv,
                                             int* __restrict__ ssrc,
                                             int* __restrict__ s32,
                                             int n, int NB, int E) {
    __shared__ int cnt[256], sc[256], cur[256];
    int b = blockIdx.x, tid = threadIdx.x;
    int node0 = b << 8;
    int i0 = b * NBLK;
    int bstart = off[i0] + boff[i0 >> 10];
    int bend = E;
    if (b + 1 < NB) {
        int i1 = (b + 1) * NBLK;
        bend = off[i1] + boff[i1 >> 10];
    }
    // padded ssrc region for this bucket
    int rbeg = bstart + b * PADSLACK;
    int rend = bend + (b + 1) * PADSLACK;
    cnt[tid] = 0;
    __syncthreads();
    for (int i = bstart + tid; i < bend; i += 256)
        atomicAdd(&cnt[ebuf[i] & 255], 1);
    // init whole padded region to sentinel (real edges overwrite below)
    for (int i = rbeg + tid; i < rend; i += 256) ssrc[i] = n;
    __syncthreads();
    int v = cnt[tid];
    int pv = (v + 8) & ~7;        // +1 self slot, padded to multiple of 8
    int val = pv;
    sc[tid] = val; __syncthreads();
    for (int o = 1; o < 256; o <<= 1) {
        int t = (tid >= o) ? sc[tid - o] : 0;
        __syncthreads();
        val += t; sc[tid] = val;
        __syncthreads();
    }
    int excl = val - pv;
    int base = rbeg + excl;
    int node = node0 + tid;
    if (node < n) {
        rowse[node] = make_int2(base, base + pv);
        dinv[node] = rsqrtf((float)v + 1.0f);
    }
    cur[tid] = base;
    __syncthreads();
    for (int i = bstart + tid; i < bend; i += 256) {
        int e = ebuf[i];
        int pos = atomicAdd(&cur[e & 255], 1);
        ssrc[pos] = e >> 8;        // s < 2^23, sign-safe
    }
    __syncthreads();
    // self slot + fixed-stride first-32 table
    if (node < n) {
        ssrc[base + v] = node;    // self-loop
        int kk[32];
#pragma unroll
        for (int k = 0; k < 32; k++) kk[k] = (k < pv) ? ssrc[base + k] : n;
        int4* d4 = (int4*)(s32 + ((size_t)node << 5));
        d4[0] = make_int4(kk[0], kk[1], kk[2], kk[3]);
        d4[1] = make_int4(kk[4], kk[5], kk[6], kk[7]);
        d4[2] = make_int4(kk[8], kk[9], kk[10], kk[11]);
        d4[3] = make_int4(kk[12], kk[13], kk[14], kk[15]);
        d4[4] = make_int4(kk[16], kk[17], kk[18], kk[19]);
        d4[5] = make_int4(kk[20], kk[21], kk[22], kk[23]);
        d4[6] = make_int4(kk[24], kk[25], kk[26], kk[27]);
        d4[7] = make_int4(kk[28], kk[29], kk[30], kk[31]);
    }
}

// --- fused cvt + prep: blocks [0,cvtBlocks) do fp32->bf16 with dinv scale;
// --- remaining blocks: weight prep + sentinel-row zeroing.
__global__ __launch_bounds__(256) void k_cvtprep(const float* __restrict__ x,
                                                 const float* __restrict__ dinv,
                                                 ushort* __restrict__ xb,
                                                 const float* __restrict__ W1,
                                                 const float* __restrict__ W2,
                                                 const float* __restrict__ b2,
                                                 const float* __restrict__ Wfc,
                                                 const float* __restrict__ bfc,
                                                 ushort* __restrict__ Wt,
                                                 ushort* __restrict__ Wct,
                                                 float* __restrict__ bc,
                                                 ushort* __restrict__ tb,
                                                 int n, int cvtBlocks) {
    if ((int)blockIdx.x < cvtBlocks) {
        int i = (blockIdx.x * 256 + threadIdx.x) * 4;
        if (i >= n * CH) return;
        float d = dinv[i >> 7];
        float4 v = *(const float4*)(x + i);
        uint2 o;
        o.x = (uint)f2bf(v.x * d) | ((uint)f2bf(v.y * d) << 16);
        o.y = (uint)f2bf(v.z * d) | ((uint)f2bf(v.w * d) << 16);
        *(uint2*)(xb + i) = o;
        return;
    }
    const int T0 = CH * CH;
    const int T1 = T0 + CH * OC;
    const int T2 = T1 + OC;
    const int T3 = T2 + CH;
    const int T4 = T3 + OC;
    int t = ((int)blockIdx.x - cvtBlocks) * 256 + threadIdx.x;
    if (t < T0) {
        int nc = t >> 7, k = t & 127;
        Wt[nc * CH + k] = f2bf(W1[k * CH + nc]);
    } else if (t < T1) {
        int u = t - T0;
        int k = u >> 6, o = u & 63;
        float acc = 0.f;
        for (int j = 0; j < CH; j++) acc += W2[k * CH + j] * Wfc[j * OC + o];
        Wct[o * CH + k] = f2bf(acc);   // [OC][CH] bf16, MFMA B-operand layout
    } else if (t < T2) {
        int o = t - T1;
        float acc = bfc[o];
        for (int j = 0; j < CH; j++) acc += b2[j] * Wfc[j * OC + o];
        bc[o] = acc;
    } else if (t < T3) {
        xb[(size_t)n * CH + (t - T2)] = 0;   // sentinel row, 128ch
    } else if (t < T4) {
        tb[(size_t)n * OC + (t - T3)] = 0;   // sentinel row, 64ch
    }
}

// ------- aggregation (128 ch): two straight-line phases via s32 ------------
// out = dinv_dst * sum(slots); slots include self; sentinel rows are zeros.
__global__ __launch_bounds__(256) void k_agg(const ushort* __restrict__ Hs,
                                             const int2* __restrict__ rowse,
                                             const int* __restrict__ ssrc,
                                             const int* __restrict__ s32,
                                             const float* __restrict__ dinv,
                                             ushort* __restrict__ out, int n) {
    int wid = (blockIdx.x << 2) | (threadIdx.x >> 6);
    if (wid >= n) return;
    int uw = __builtin_amdgcn_readfirstlane(wid);
    int lane = threadIdx.x & 63;
    int sub = lane >> 4;          // 4 slot groups
    int li = lane & 15;
    int c = li * 8;               // 8 bf16 channels = 16 B per lane
    const int* srow = s32 + ((size_t)uw << 5);
    int4 sa = *(const int4*)(srow + sub * 4);        // slots 0..15
    int4 sb = *(const int4*)(srow + 16 + sub * 4);   // slots 16..31
    int2 se = rowse[uw];
    int pv = se.y - se.x;
    float a0 = 0.f, a1 = 0.f, a2 = 0.f, a3 = 0.f;
    float a4 = 0.f, a5 = 0.f, a6 = 0.f, a7 = 0.f;
    {   // phase A
        uint4 g0 = *(const uint4*)(Hs + (sa.x << 7) + c);
        uint4 g1 = *(const uint4*)(Hs + (sa.y << 7) + c);
        uint4 g2 = *(const uint4*)(Hs + (sa.z << 7) + c);
        uint4 g3 = *(const uint4*)(Hs + (sa.w << 7) + c);
        acc8(g0, a0, a1, a2, a3, a4, a5, a6, a7);
        acc8(g1, a0, a1, a2, a3, a4, a5, a6, a7);
        acc8(g2, a0, a1, a2, a3, a4, a5, a6, a7);
        acc8(g3, a0, a1, a2, a3, a4, a5, a6, a7);
    }
    if (pv > 16) {   // phase B (wave-uniform branch)
        uint4 g0 = *(const uint4*)(Hs + (sb.x << 7) + c);
        uint4 g1 = *(const uint4*)(Hs + (sb.y << 7) + c);
        uint4 g2 = *(const uint4*)(Hs + (sb.z << 7) + c);
        uint4 g3 = *(const uint4*)(Hs + (sb.w << 7) + c);
        acc8(g0, a0, a1, a2, a3, a4, a5, a6, a7);
        acc8(g1, a0, a1, a2, a3, a4, a5, a6, a7);
        acc8(g2, a0, a1, a2, a3, a4, a5, a6, a7);
        acc8(g3, a0, a1, a2, a3, a4, a5, a6, a7);
        if (pv > 32) {   // rare heavy nodes
            int e = se.x + 32, e1 = se.y;
            for (; e + 16 <= e1; e += 16) {
                int s0 = ssrc[e + sub];
                int s1 = ssrc[e + 4 + sub];
                int s2 = ssrc[e + 8 + sub];
                int s3 = ssrc[e + 12 + sub];
                uint4 g0 = *(const uint4*)(Hs + (s0 << 7) + c);
                uint4 g1 = *(const uint4*)(Hs + (s1 << 7) + c);
                uint4 g2 = *(const uint4*)(Hs + (s2 << 7) + c);
                uint4 g3 = *(const uint4*)(Hs + (s3 << 7) + c);
                acc8(g0, a0, a1, a2, a3, a4, a5, a6, a7);
                acc8(g1, a0, a1, a2, a3, a4, a5, a6, a7);
                acc8(g2, a0, a1, a2, a3, a4, a5, a6, a7);
                acc8(g3, a0, a1, a2, a3, a4, a5, a6, a7);
            }
            if (e < e1) {   // exactly 8 remaining
                int s0 = ssrc[e + sub];
                int s1 = ssrc[e + 4 + sub];
                uint4 g0 = *(const uint4*)(Hs + (s0 << 7) + c);
                uint4 g1 = *(const uint4*)(Hs + (s1 << 7) + c);
                acc8(g0, a0, a1, a2, a3, a4, a5, a6, a7);
                acc8(g1, a0, a1, a2, a3, a4, a5, a6, a7);
            }
        }
    }
    a0 += __shfl_xor(a0, 16); a0 += __shfl_xor(a0, 32);
    a1 += __shfl_xor(a1, 16); a1 += __shfl_xor(a1, 32);
    a2 += __shfl_xor(a2, 16); a2 += __shfl_xor(a2, 32);
    a3 += __shfl_xor(a3, 16); a3 += __shfl_xor(a3, 32);
    a4 += __shfl_xor(a4, 16); a4 += __shfl_xor(a4, 32);
    a5 += __shfl_xor(a5, 16); a5 += __shfl_xor(a5, 32);
    a6 += __shfl_xor(a6, 16); a6 += __shfl_xor(a6, 32);
    a7 += __shfl_xor(a7, 16); a7 += __shfl_xor(a7, 32);
    if (sub == 0) {
        float d = dinv[uw];
        uint4 o;
        o.x = (uint)f2bf(a0 * d) | ((uint)f2bf(a1 * d) << 16);
        o.y = (uint)f2bf(a2 * d) | ((uint)f2bf(a3 * d) << 16);
        o.z = (uint)f2bf(a4 * d) | ((uint)f2bf(a5 * d) << 16);
        o.w = (uint)f2bf(a6 * d) | ((uint)f2bf(a7 * d) << 16);
        *(uint4*)(out + ((size_t)uw << 7) + c) = o;
    }
}

// ------- aggregation (64 ch): straight-line phases, bf16 z-row write --------
__global__ __launch_bounds__(256) void k_agg64(const ushort* __restrict__ Hs,
                                               const int2* __restrict__ rowse,
                                               const int* __restrict__ ssrc,
                                               const int* __restrict__ s32,
                                               const float* __restrict__ dinv,
                                               ushort* __restrict__ out, int n) {
    int wid = (blockIdx.x << 2) | (threadIdx.x >> 6);
    if (wid >= n) return;
    int uw = __builtin_amdgcn_readfirstlane(wid);
    int lane = threadIdx.x & 63;
    int sub = lane >> 3;          // 8 slot groups
    int li = lane & 7;
    int c = li * 8;               // 8 bf16 channels = 16 B per lane
    const int* srow = s32 + ((size_t)uw << 5);
    int2 sa = *(const int2*)(srow + sub * 2);        // slots 0..15
    int2 sb = *(const int2*)(srow + 16 + sub * 2);   // slots 16..31
    int2 se = rowse[uw];
    int pv = se.y - se.x;
    float a0 = 0.f, a1 = 0.f, a2 = 0.f, a3 = 0.f;
    float a4 = 0.f, a5 = 0.f, a6 = 0.f, a7 = 0.f;
    {   // phase A
        uint4 g0 = *(const uint4*)(Hs + (sa.x << 6) + c);
        uint4 g1 = *(const uint4*)(Hs + (sa.y << 6) + c);
        acc8(g0, a0, a1, a2, a3, a4, a5, a6, a7);
        acc8(g1, a0, a1, a2, a3, a4, a5, a6, a7);
    }
    if (pv > 16) {   // phase B
        uint4 g0 = *(const uint4*)(Hs + (sb.x << 6) + c);
        uint4 g1 = *(const uint4*)(Hs + (sb.y << 6) + c);
        acc8(g0, a0, a1, a2, a3, a4, a5, a6, a7);
        acc8(g1, a0, a1, a2, a3, a4, a5, a6, a7);
        if (pv > 32) {   // rare heavy nodes
            int e = se.x + 32, e1 = se.y;
            for (; e + 16 <= e1; e += 16) {
                int s0 = ssrc[e + sub];
                int s1 = ssrc[e + 8 + sub];
                uint4 g0 = *(const uint4*)(Hs + (s0 << 6) + c);
                uint4 g1 = *(const uint4*)(Hs + (s1 << 6) + c);
                acc8(g0, a0, a1, a2, a3, a4, a5, a6, a7);
                acc8(g1, a0, a1, a2, a3, a4, a5, a6, a7);
            }
            if (e < e1) {   // exactly 8 remaining
                int s0 = ssrc[e + sub];
                uint4 g0 = *(const uint4*)(Hs + (s0 << 6) + c);
                acc8(g0, a0, a1, a2, a3, a4, a5, a6, a7);
            }
        }
    }
    a0 += __shfl_xor(a0, 8); a0 += __shfl_xor(a0, 16); a0 += __shfl_xor(a0, 32);
    a1 += __shfl_xor(a1, 8); a1 += __shfl_xor(a1, 16); a1 += __shfl_xor(a1, 32);
    a2 += __shfl_xor(a2, 8); a2 += __shfl_xor(a2, 16); a2 += __shfl_xor(a2, 32);
    a3 += __shfl_xor(a3, 8); a3 += __shfl_xor(a3, 16); a3 += __shfl_xor(a3, 32);
    a4 += __shfl_xor(a4, 8); a4 += __shfl_xor(a4, 16); a4 += __shfl_xor(a4, 32);
    a5 += __shfl_xor(a5, 8); a5 += __shfl_xor(a5, 16); a5 += __shfl_xor(a5, 32);
    a6 += __shfl_xor(a6, 8); a6 += __shfl_xor(a6, 16); a6 += __shfl_xor(a6, 32);
    a7 += __shfl_xor(a7, 8); a7 += __shfl_xor(a7, 16); a7 += __shfl_xor(a7, 32);
    if (sub == 0) {
        float d = dinv[uw];
        uint4 o;
        o.x = (uint)f2bf(a0 * d) | ((uint)f2bf(a1 * d) << 16);
        o.y = (uint)f2bf(a2 * d) | ((uint)f2bf(a3 * d) << 16);
        o.z = (uint)f2bf(a4 * d) | ((uint)f2bf(a5 * d) << 16);
        o.w = (uint)f2bf(a6 * d) | ((uint)f2bf(a7 * d) << 16);
        *(uint4*)(out + ((size_t)uw << 6) + c) = o;
    }
}

// ---- T = (dinv*relu(Y*W1 + b1)) * Wct : two MFMA stages, LDS tile reuse ----
__global__ __launch_bounds__(256) void k_gemm_mfma(const ushort* __restrict__ Y,
                                                   const ushort* __restrict__ Wt,
                                                   const float* __restrict__ bias,
                                                   const float* __restrict__ dinv,
                                                   const ushort* __restrict__ Wct,
                                                   ushort* __restrict__ T, int n) {
    __shared__ __align__(16) ushort As[128][136];
    int tid = threadIdx.x;
    int r0 = blockIdx.x * 128;
#pragma unroll
    for (int i = 0; i < 8; i++) {
        int idx = tid + i * 256;
        int row = idx >> 4;
        int c8 = (idx & 15) * 8;
        int r = r0 + row;
        uint4 v = make_uint4(0u, 0u, 0u, 0u);
        if (r < n) v = *(const uint4*)(Y + (size_t)r * CH + c8);
        *(uint4*)&As[row][c8] = v;
    }
    __syncthreads();
    int w = tid >> 6, lane = tid & 63;
    int qm = lane & 15, quad = lane >> 4;
    floatx4 acc[2][8];
#pragma unroll
    for (int mi = 0; mi < 2; mi++)
#pragma unroll
        for (int nt = 0; nt < 8; nt++) acc[mi][nt] = (floatx4){0.f, 0.f, 0.f, 0.f};
#pragma unroll
    for (int ks = 0; ks < 4; ks++) {
        int k0 = ks * 32 + quad * 8;
        short8 va0 = *(const short8*)&As[w * 32 + qm][k0];
        short8 va1 = *(const short8*)&As[w * 32 + 16 + qm][k0];
#pragma unroll
        for (int nt = 0; nt < 8; nt++) {
            short8 b = *(const short8*)(Wt + (nt * 16 + qm) * CH + k0);
            acc[0][nt] = __builtin_amdgcn_mfma_f32_16x16x32_bf16(va0, b, acc[0][nt], 0, 0, 0);
            acc[1][nt] = __builtin_amdgcn_mfma_f32_16x16x32_bf16(va1, b, acc[1][nt], 0, 0, 0);
        }
    }
    // epilogue stage 1: hs = dinv*relu(acc+bias), write bf16 back to own rows
#pragma unroll
    for (int mi = 0; mi < 2; mi++) {
#pragma unroll
        for (int reg = 0; reg < 4; reg++) {
            int lrow = w * 32 + mi * 16 + quad * 4 + reg;
            int r = r0 + lrow;
            float d = (r < n) ? dinv[r] : 0.f;   // pad rows -> exact 0
#pragma unroll
            for (int nt = 0; nt < 8; nt++) {
                int cidx = nt * 16 + qm;
                float val = fmaxf(acc[mi][nt][reg] + bias[cidx], 0.f) * d;
                As[lrow][cidx] = f2bf(val);
            }
        }
    }
    __syncthreads();
    // stage 2: T tile = hs(128x128) * Wct(64x128)^T
    floatx4 acc2[2][4];
#pragma unroll
    for (int mi = 0; mi < 2; mi++)
#pragma unroll
        for (int nt = 0; nt < 4; nt++) acc2[mi][nt] = (floatx4){0.f, 0.f, 0.f, 0.f};
#pragma unroll
    for (int ks = 0; ks < 4; ks++) {
        int k0 = ks * 32 + quad * 8;
        short8 va0 = *(const short8*)&As[w * 32 + qm][k0];
        short8 va1 = *(const short8*)&As[w * 32 + 16 + qm][k0];
#pragma unroll
        for (int nt = 0; nt < 4; nt++) {
            short8 b = *(const short8*)(Wct + (nt * 16 + qm) * CH + k0);
            acc2[0][nt] = __builtin_amdgcn_mfma_f32_16x16x32_bf16(va0, b, acc2[0][nt], 0, 0, 0);
            acc2[1][nt] = __builtin_amdgcn_mfma_f32_16x16x32_bf16(va1, b, acc2[1][nt], 0, 0, 0);
        }
    }
#pragma unroll
    for (int mi = 0; mi < 2; mi++) {
#pragma unroll
        for (int reg = 0; reg < 4; reg++) {
            int r = r0 + w * 32 + mi * 16 + quad * 4 + reg;
            if (r >= n) continue;
#pragma unroll
            for (int nt = 0; nt < 4; nt++)
                T[(size_t)r * OC + nt * 16 + qm] = f2bf(acc2[mi][nt][reg]);
        }
    }
}

// ---- fused pool+out: one block per graph, binary-search node range,
// ---- block-reduce 64 channels, write out = mean + bc directly.
__global__ __launch_bounds__(256) void k_poolout(const ushort* __restrict__ Z,
                                                 const int* __restrict__ batch,
                                                 const float* __restrict__ bc,
                                                 float* __restrict__ out, int n) {
    __shared__ float red[4][OC];
    int g = blockIdx.x;
    // lower_bound(batch, g) and lower_bound(batch, g+1)
    int lo = 0, hi = n;
    while (lo < hi) { int m = (lo + hi) >> 1; if (batch[m] < g) lo = m + 1; else hi = m; }
    int beg = lo;
    hi = n;
    while (lo < hi) { int m = (lo + hi) >> 1; if (batch[m] < g + 1) lo = m + 1; else hi = m; }
    int end = lo;
    int w = threadIdx.x >> 6, lane = threadIdx.x & 63;
    float a = 0.f;
    for (int i = beg + w; i < end; i += 4)
        a += __uint_as_float(((uint)Z[(size_t)i * OC + lane]) << 16);
    red[w][lane] = a;
    __syncthreads();
    if (w == 0) {
        float s = red[0][lane] + red[1][lane] + red[2][lane] + red[3][lane];
        float invc = 1.f / fmaxf((float)(end - beg), 1.f);
        out[g * OC + lane] = s * invc + bc[lane];
    }
}

extern "C" void kernel_launch(void* const* d_in, const int* in_sizes, int n_in,
                              void* d_out, int out_size, void* d_ws, size_t ws_size,
                              hipStream_t stream) {
    const float* x   = (const float*)d_in[0];
    const float* W1  = (const float*)d_in[1];
    const float* b1  = (const float*)d_in[2];
    const float* W2  = (const float*)d_in[3];
    const float* b2  = (const float*)d_in[4];
    const float* Wfc = (const float*)d_in[5];
    const float* bfc = (const float*)d_in[6];
    const int* edges = (const int*)d_in[7];
    const int* batch = (const int*)d_in[8];

    const int n = in_sizes[8];        // 100000
    const int E = in_sizes[7] / 2;    // 1600000
    const int* esrc = edges;
    const int* edst = edges + E;

    const int NB = (n + 255) >> 8;            // 391 coarse buckets
    const int T = NB * NBLK;
    const int chunk = (E + NBLK - 1) / NBLK;

    char* p = (char*)d_ws;
    auto carve = [&](size_t bytes) {
        void* r = (void*)p;
        p += (bytes + 255) & ~(size_t)255;
        return r;
    };
    int*    bhT       = (int*)carve((size_t)T * 4);
    int*    off       = (int*)carve((size_t)T * 4);
    int*    bsums     = (int*)carve(512);
    int*    ebuf      = (int*)carve((size_t)E * 4);
    int2*   rowse     = (int2*)carve((size_t)n * 8);
    float*  dinv      = (float*)carve((size_t)n * 4);
    int*    ssrc      = (int*)carve(((size_t)E + (size_t)NB * PADSLACK + 256) * 4);
    int*    s32       = (int*)carve((size_t)n * 32 * 4);
    ushort* xb        = (ushort*)carve((size_t)(n + 1) * CH * 2);  // +sentinel row
    ushort* yb        = (ushort*)carve((size_t)n * CH * 2);
    ushort* tb        = (ushort*)carve((size_t)(n + 1) * OC * 2);  // +sentinel row
    ushort* Wt        = (ushort*)carve((size_t)CH * CH * 2);
    ushort* Wct       = (ushort*)carve((size_t)OC * CH * 2);
    float*  bc        = (float*)carve((size_t)OC * 4);

    int nScanBlocks = (T + 1023) / 1024;
    int cvtBlocks = (n * CH / 4 + 255) / 256;
    int prepBlocks = (CH * CH + CH * OC + OC + CH + OC + 255) / 256;

    // CSR build (atomic-free global ordering; rows = edges+self padded to x8)
    k_hist<<<NBLK, 256, 0, stream>>>(edst, bhT, E, NB, chunk);
    k_scan1<<<nScanBlocks, 256, 0, stream>>>(bhT, off, bsums, T);
    k_scan2<<<1, 128, 0, stream>>>(bsums, nScanBlocks);
    k_part<<<NBLK, 256, 0, stream>>>(esrc, edst, off, bsums, ebuf, E, NB, chunk);
    k_csr<<<NB, 256, 0, stream>>>(ebuf, off, bsums, rowse, dinv, ssrc, s32, n, NB, E);

    // fused features + weight prep (also zeroes sentinel rows of xb/tb)
    k_cvtprep<<<cvtBlocks + prepBlocks, 256, 0, stream>>>(
        x, dinv, xb, W1, W2, b2, Wfc, bfc, Wt, Wct, bc, tb, n, cvtBlocks);
    // y = dinv*(sum slots incl self)   (xb -> yb, 128 ch)
    k_agg<<<(n + 3) / 4, 256, 0, stream>>>(xb, rowse, ssrc, s32, dinv, yb, n);
    // t = (dinv*relu(y*W1 + b1)) * Wct   (yb -> tb, 64 ch)
    k_gemm_mfma<<<(n + 127) / 128, 256, 0, stream>>>(yb, Wt, b1, dinv, Wct, tb, n);
    // z = dinv*(sum slots incl self)   (tb -> xb-as-64ch)
    k_agg64<<<(n + 3) / 4, 256, 0, stream>>>(tb, rowse, ssrc, s32, dinv, xb, n);
    // out = mean-pool(z) + bc   (one block per graph, no atomics)
    k_poolout<<<NG, 256, 0, stream>>>(xb, batch, bc, (float*)d_out, n);
}

// Round 7
// 310.419 us; speedup vs baseline: 2.0336x; 1.0063x over previous
//
#include <hip/hip_runtime.h>
#include <stdint.h>

#define NN 100000
#define NE 1600000
#define CH 128
#define OC 64
#define NG 512
#define NBLK 256      // partition blocks
#define NBMAX 4096    // max coarse buckets (nodes/256)
#define PADSLACK 2048 // per-bucket ssrc slack: 256 nodes * 8 (self + pad to x8)

typedef unsigned int uint;
typedef unsigned short ushort;
typedef __attribute__((ext_vector_type(8))) short short8;
typedef __attribute__((ext_vector_type(4))) float floatx4;

__device__ __forceinline__ ushort f2bf(float f) {
    uint u = __float_as_uint(f);
    uint r = u + 0x7fffu + ((u >> 16) & 1u);  // round-to-nearest-even
    return (ushort)(r >> 16);
}
__device__ __forceinline__ float bf_lo(uint g) { return __uint_as_float(g << 16); }
__device__ __forceinline__ float bf_hi(uint g) { return __uint_as_float(g & 0xffff0000u); }

__device__ __forceinline__ void acc8(uint4 g, float& a0, float& a1, float& a2, float& a3,
                                     float& a4, float& a5, float& a6, float& a7) {
    a0 += bf_lo(g.x); a1 += bf_hi(g.x);
    a2 += bf_lo(g.y); a3 += bf_hi(g.y);
    a4 += bf_lo(g.z); a5 += bf_hi(g.z);
    a6 += bf_lo(g.w); a7 += bf_hi(g.w);
}

// ---------------- bucket histogram, written bucket-major ----------------
__global__ __launch_bounds__(256) void k_hist(const int* __restrict__ dst,
                                              int* __restrict__ bhT,
                                              int E, int NB, int chunk) {
    __shared__ int h[NBMAX];
    int blk = blockIdx.x, tid = threadIdx.x;
    for (int j = tid; j < NB; j += 256) h[j] = 0;
    __syncthreads();
    int lo = blk * chunk, hi = min(E, lo + chunk);
    for (int i = lo + tid; i < hi; i += 256) atomicAdd(&h[dst[i] >> 8], 1);
    __syncthreads();
    for (int j = tid; j < NB; j += 256) bhT[j * NBLK + blk] = h[j];
}

// ---------------- prefix scan (2-phase; block offsets folded by consumers) ---
__global__ __launch_bounds__(256) void k_scan1(const int* __restrict__ in,
                                               int* __restrict__ excl,
                                               int* __restrict__ bsums, int T) {
    __shared__ int sd[256];
    int tid = threadIdx.x;
    int base = blockIdx.x * 1024 + tid * 4;
    int v[4];
#pragma unroll
    for (int i = 0; i < 4; i++) v[i] = (base + i < T) ? in[base + i] : 0;
    int tsum = v[0] + v[1] + v[2] + v[3];
    int val = tsum;
    sd[tid] = val; __syncthreads();
    for (int off = 1; off < 256; off <<= 1) {
        int t = (tid >= off) ? sd[tid - off] : 0;
        __syncthreads();
        val += t; sd[tid] = val;
        __syncthreads();
    }
    int run = val - tsum;
#pragma unroll
    for (int i = 0; i < 4; i++) {
        if (base + i < T) excl[base + i] = run;
        run += v[i];
    }
    if (tid == 255) bsums[blockIdx.x] = val;
}

__global__ __launch_bounds__(128) void k_scan2(int* __restrict__ bs, int nb) {
    __shared__ int sd[128];
    int tid = threadIdx.x;
    int v = (tid < nb) ? bs[tid] : 0;
    int val = v;
    sd[tid] = val; __syncthreads();
    for (int off = 1; off < 128; off <<= 1) {
        int t = (tid >= off) ? sd[tid - off] : 0;
        __syncthreads();
        val += t; sd[tid] = val;
        __syncthreads();
    }
    if (tid < nb) bs[tid] = val - v;
}

// ------- partition: packed (src<<8)|(dst&255) into per-(bucket,block) segs ----
__global__ __launch_bounds__(256) void k_part(const int* __restrict__ src,
                                              const int* __restrict__ dst,
                                              const int* __restrict__ off,
                                              const int* __restrict__ boff,
                                              int* __restrict__ ebuf,
                                              int E, int NB, int chunk) {
    __shared__ int cur[NBMAX];
    int blk = blockIdx.x, tid = threadIdx.x;
    for (int j = tid; j < NB; j += 256) {
        int idx = j * NBLK + blk;
        cur[j] = off[idx] + boff[idx >> 10];
    }
    __syncthreads();
    int lo = blk * chunk, hi = min(E, lo + chunk);
    for (int i = lo + tid; i < hi; i += 256) {
        int s = src[i], d = dst[i];
        int pos = atomicAdd(&cur[d >> 8], 1);
        ebuf[pos] = (s << 8) | (d & 255);
    }
}

// ------- CSR finalize per bucket: deg, dinv, (start,end), padded scatter -----
// Row layout: [deg real edges][self node][pad to x8 with sentinel n].
// Emits s32[node][32]: first 32 slots at fixed stride -> straight-line aggs.
__global__ __launch_bounds__(256) void k_csr(const int* __restrict__ ebuf,
                                             const int* __restrict__ off,
                                             const int* __restrict__ boff,
                                             int2* __restrict__ rowse,
                                             float* __restrict__ dinv,
                                             int* __restrict__ ssrc,
                                             int* __restrict__ s32,
                                             int n, int NB, int E) {
    __shared__ int cnt[256], sc[256], cur[256];
    int b = blockIdx.x, tid = threadIdx.x;
    int node0 = b << 8;
    int i0 = b * NBLK;
    int bstart = off[i0] + boff[i0 >> 10];
    int bend = E;
    if (b + 1 < NB) {
        int i1 = (b + 1) * NBLK;
        bend = off[i1] + boff[i1 >> 10];
    }
    // padded ssrc region for this bucket
    int rbeg = bstart + b * PADSLACK;
    int rend = bend + (b + 1) * PADSLACK;
    cnt[tid] = 0;
    __syncthreads();
    for (int i = bstart + tid; i < bend; i += 256)
        atomicAdd(&cnt[ebuf[i] & 255], 1);
    // init whole padded region to sentinel (real edges overwrite below)
    for (int i = rbeg + tid; i < rend; i += 256) ssrc[i] = n;
    __syncthreads();
    int v = cnt[tid];
    int pv = (v + 8) & ~7;        // +1 self slot, padded to multiple of 8
    int val = pv;
    sc[tid] = val; __syncthreads();
    for (int o = 1; o < 256; o <<= 1) {
        int t = (tid >= o) ? sc[tid - o] : 0;
        __syncthreads();
        val += t; sc[tid] = val;
        __syncthreads();
    }
    int excl = val - pv;
    int base = rbeg + excl;
    int node = node0 + tid;
    if (node < n) {
        rowse[node] = make_int2(base, base + pv);
        dinv[node] = rsqrtf((float)v + 1.0f);
    }
    cur[tid] = base;
    __syncthreads();
    for (int i = bstart + tid; i < bend; i += 256) {
        int e = ebuf[i];
        int pos = atomicAdd(&cur[e & 255], 1);
        ssrc[pos] = e >> 8;        // s < 2^23, sign-safe
    }
    __syncthreads();
    // self slot + fixed-stride first-32 table
    if (node < n) {
        ssrc[base + v] = node;    // self-loop
        int kk[32];
#pragma unroll
        for (int k = 0; k < 32; k++) kk[k] = (k < pv) ? ssrc[base + k] : n;
        int4* d4 = (int4*)(s32 + ((size_t)node << 5));
        d4[0] = make_int4(kk[0], kk[1], kk[2], kk[3]);
        d4[1] = make_int4(kk[4], kk[5], kk[6], kk[7]);
        d4[2] = make_int4(kk[8], kk[9], kk[10], kk[11]);
        d4[3] = make_int4(kk[12], kk[13], kk[14], kk[15]);
        d4[4] = make_int4(kk[16], kk[17], kk[18], kk[19]);
        d4[5] = make_int4(kk[20], kk[21], kk[22], kk[23]);
        d4[6] = make_int4(kk[24], kk[25], kk[26], kk[27]);
        d4[7] = make_int4(kk[28], kk[29], kk[30], kk[31]);
    }
}

// --- fused cvt + prep: blocks [0,cvtBlocks) do fp32->bf16 with dinv scale;
// --- remaining blocks: weight prep + sentinel-row zeroing.
__global__ __launch_bounds__(256) void k_cvtprep(const float* __restrict__ x,
                                                 const float* __restrict__ dinv,
                                                 ushort* __restrict__ xb,
                                                 const float* __restrict__ W1,
                                                 const float* __restrict__ W2,
                                                 const float* __restrict__ b2,
                                                 const float* __restrict__ Wfc,
                                                 const float* __restrict__ bfc,
                                                 ushort* __restrict__ Wt,
                                                 ushort* __restrict__ Wct,
                                                 float* __restrict__ bc,
                                                 ushort* __restrict__ tb,
                                                 int n, int cvtBlocks) {
    if ((int)blockIdx.x < cvtBlocks) {
        int i = (blockIdx.x * 256 + threadIdx.x) * 4;
        if (i >= n * CH) return;
        float d = dinv[i >> 7];
        float4 v = *(const float4*)(x + i);
        uint2 o;
        o.x = (uint)f2bf(v.x * d) | ((uint)f2bf(v.y * d) << 16);
        o.y = (uint)f2bf(v.z * d) | ((uint)f2bf(v.w * d) << 16);
        *(uint2*)(xb + i) = o;
        return;
    }
    const int T0 = CH * CH;
    const int T1 = T0 + CH * OC;
    const int T2 = T1 + OC;
    const int T3 = T2 + CH;
    const int T4 = T3 + OC;
    int t = ((int)blockIdx.x - cvtBlocks) * 256 + threadIdx.x;
    if (t < T0) {
        int nc = t >> 7, k = t & 127;
        Wt[nc * CH + k] = f2bf(W1[k * CH + nc]);
    } else if (t < T1) {
        int u = t - T0;
        int k = u >> 6, o = u & 63;
        float acc = 0.f;
        for (int j = 0; j < CH; j++) acc += W2[k * CH + j] * Wfc[j * OC + o];
        Wct[o * CH + k] = f2bf(acc);   // [OC][CH] bf16, MFMA B-operand layout
    } else if (t < T2) {
        int o = t - T1;
        float acc = bfc[o];
        for (int j = 0; j < CH; j++) acc += b2[j] * Wfc[j * OC + o];
        bc[o] = acc;
    } else if (t < T3) {
        xb[(size_t)n * CH + (t - T2)] = 0;   // sentinel row, 128ch
    } else if (t < T4) {
        tb[(size_t)n * OC + (t - T3)] = 0;   // sentinel row, 64ch
    }
}

// ------- aggregation (128 ch): branchless 32-slot gather via s32 ------------
// All 8 uint4 gathers issued up-front (sentinel slots read the zero row ->
// L1-hit, exact +0). Only the rare pv>32 continuation remains branched.
__global__ __launch_bounds__(256) void k_agg(const ushort* __restrict__ Hs,
                                             const int2* __restrict__ rowse,
                                             const int* __restrict__ ssrc,
                                             const int* __restrict__ s32,
                                             const float* __restrict__ dinv,
                                             ushort* __restrict__ out, int n) {
    int wid = (blockIdx.x << 2) | (threadIdx.x >> 6);
    if (wid >= n) return;
    int uw = __builtin_amdgcn_readfirstlane(wid);
    int lane = threadIdx.x & 63;
    int sub = lane >> 4;          // 4 slot groups
    int li = lane & 15;
    int c = li * 8;               // 8 bf16 channels = 16 B per lane
    const int* srow = s32 + ((size_t)uw << 5);
    int4 sa = *(const int4*)(srow + sub * 4);        // slots 4sub..4sub+3
    int4 sb = *(const int4*)(srow + 16 + sub * 4);   // slots 16+4sub..
    int2 se = rowse[uw];
    // issue all 8 gathers back-to-back (max memory-level parallelism)
    uint4 g0 = *(const uint4*)(Hs + (sa.x << 7) + c);
    uint4 g1 = *(const uint4*)(Hs + (sa.y << 7) + c);
    uint4 g2 = *(const uint4*)(Hs + (sa.z << 7) + c);
    uint4 g3 = *(const uint4*)(Hs + (sa.w << 7) + c);
    uint4 g4 = *(const uint4*)(Hs + (sb.x << 7) + c);
    uint4 g5 = *(const uint4*)(Hs + (sb.y << 7) + c);
    uint4 g6 = *(const uint4*)(Hs + (sb.z << 7) + c);
    uint4 g7 = *(const uint4*)(Hs + (sb.w << 7) + c);
    float a0 = 0.f, a1 = 0.f, a2 = 0.f, a3 = 0.f;
    float a4 = 0.f, a5 = 0.f, a6 = 0.f, a7 = 0.f;
    acc8(g0, a0, a1, a2, a3, a4, a5, a6, a7);
    acc8(g1, a0, a1, a2, a3, a4, a5, a6, a7);
    acc8(g2, a0, a1, a2, a3, a4, a5, a6, a7);
    acc8(g3, a0, a1, a2, a3, a4, a5, a6, a7);
    acc8(g4, a0, a1, a2, a3, a4, a5, a6, a7);
    acc8(g5, a0, a1, a2, a3, a4, a5, a6, a7);
    acc8(g6, a0, a1, a2, a3, a4, a5, a6, a7);
    acc8(g7, a0, a1, a2, a3, a4, a5, a6, a7);
    if (se.y - se.x > 32) {   // rare heavy nodes
        int e = se.x + 32, e1 = se.y;
        for (; e + 16 <= e1; e += 16) {
            int s0 = ssrc[e + sub];
            int s1 = ssrc[e + 4 + sub];
            int s2 = ssrc[e + 8 + sub];
            int s3 = ssrc[e + 12 + sub];
            uint4 h0 = *(const uint4*)(Hs + (s0 << 7) + c);
            uint4 h1 = *(const uint4*)(Hs + (s1 << 7) + c);
            uint4 h2 = *(const uint4*)(Hs + (s2 << 7) + c);
            uint4 h3 = *(const uint4*)(Hs + (s3 << 7) + c);
            acc8(h0, a0, a1, a2, a3, a4, a5, a6, a7);
            acc8(h1, a0, a1, a2, a3, a4, a5, a6, a7);
            acc8(h2, a0, a1, a2, a3, a4, a5, a6, a7);
            acc8(h3, a0, a1, a2, a3, a4, a5, a6, a7);
        }
        if (e < e1) {   // exactly 8 remaining
            int s0 = ssrc[e + sub];
            int s1 = ssrc[e + 4 + sub];
            uint4 h0 = *(const uint4*)(Hs + (s0 << 7) + c);
            uint4 h1 = *(const uint4*)(Hs + (s1 << 7) + c);
            acc8(h0, a0, a1, a2, a3, a4, a5, a6, a7);
            acc8(h1, a0, a1, a2, a3, a4, a5, a6, a7);
        }
    }
    a0 += __shfl_xor(a0, 16); a0 += __shfl_xor(a0, 32);
    a1 += __shfl_xor(a1, 16); a1 += __shfl_xor(a1, 32);
    a2 += __shfl_xor(a2, 16); a2 += __shfl_xor(a2, 32);
    a3 += __shfl_xor(a3, 16); a3 += __shfl_xor(a3, 32);
    a4 += __shfl_xor(a4, 16); a4 += __shfl_xor(a4, 32);
    a5 += __shfl_xor(a5, 16); a5 += __shfl_xor(a5, 32);
    a6 += __shfl_xor(a6, 16); a6 += __shfl_xor(a6, 32);
    a7 += __shfl_xor(a7, 16); a7 += __shfl_xor(a7, 32);
    if (sub == 0) {
        float d = dinv[uw];
        uint4 o;
        o.x = (uint)f2bf(a0 * d) | ((uint)f2bf(a1 * d) << 16);
        o.y = (uint)f2bf(a2 * d) | ((uint)f2bf(a3 * d) << 16);
        o.z = (uint)f2bf(a4 * d) | ((uint)f2bf(a5 * d) << 16);
        o.w = (uint)f2bf(a6 * d) | ((uint)f2bf(a7 * d) << 16);
        *(uint4*)(out + ((size_t)uw << 7) + c) = o;
    }
}

// ------- aggregation (64 ch): branchless 32-slot gather, bf16 z write -------
__global__ __launch_bounds__(256) void k_agg64(const ushort* __restrict__ Hs,
                                               const int2* __restrict__ rowse,
                                               const int* __restrict__ ssrc,
                                               const int* __restrict__ s32,
                                               const float* __restrict__ dinv,
                                               ushort* __restrict__ out, int n) {
    int wid = (blockIdx.x << 2) | (threadIdx.x >> 6);
    if (wid >= n) return;
    int uw = __builtin_amdgcn_readfirstlane(wid);
    int lane = threadIdx.x & 63;
    int sub = lane >> 3;          // 8 slot groups
    int li = lane & 7;
    int c = li * 8;               // 8 bf16 channels = 16 B per lane
    const int* srow = s32 + ((size_t)uw << 5);
    int4 sa = *(const int4*)(srow + sub * 4);        // slots 4sub..4sub+3
    int2 se = rowse[uw];
    uint4 g0 = *(const uint4*)(Hs + (sa.x << 6) + c);
    uint4 g1 = *(const uint4*)(Hs + (sa.y << 6) + c);
    uint4 g2 = *(const uint4*)(Hs + (sa.z << 6) + c);
    uint4 g3 = *(const uint4*)(Hs + (sa.w << 6) + c);
    float a0 = 0.f, a1 = 0.f, a2 = 0.f, a3 = 0.f;
    float a4 = 0.f, a5 = 0.f, a6 = 0.f, a7 = 0.f;
    acc8(g0, a0, a1, a2, a3, a4, a5, a6, a7);
    acc8(g1, a0, a1, a2, a3, a4, a5, a6, a7);
    acc8(g2, a0, a1, a2, a3, a4, a5, a6, a7);
    acc8(g3, a0, a1, a2, a3, a4, a5, a6, a7);
    if (se.y - se.x > 32) {   // rare heavy nodes
        int e = se.x + 32, e1 = se.y;
        for (; e + 16 <= e1; e += 16) {
            int s0 = ssrc[e + sub];
            int s1 = ssrc[e + 8 + sub];
            uint4 h0 = *(const uint4*)(Hs + (s0 << 6) + c);
            uint4 h1 = *(const uint4*)(Hs + (s1 << 6) + c);
            acc8(h0, a0, a1, a2, a3, a4, a5, a6, a7);
            acc8(h1, a0, a1, a2, a3, a4, a5, a6, a7);
        }
        if (e < e1) {   // exactly 8 remaining
            int s0 = ssrc[e + sub];
            uint4 h0 = *(const uint4*)(Hs + (s0 << 6) + c);
            acc8(h0, a0, a1, a2, a3, a4, a5, a6, a7);
        }
    }
    a0 += __shfl_xor(a0, 8); a0 += __shfl_xor(a0, 16); a0 += __shfl_xor(a0, 32);
    a1 += __shfl_xor(a1, 8); a1 += __shfl_xor(a1, 16); a1 += __shfl_xor(a1, 32);
    a2 += __shfl_xor(a2, 8); a2 += __shfl_xor(a2, 16); a2 += __shfl_xor(a2, 32);
    a3 += __shfl_xor(a3, 8); a3 += __shfl_xor(a3, 16); a3 += __shfl_xor(a3, 32);
    a4 += __shfl_xor(a4, 8); a4 += __shfl_xor(a4, 16); a4 += __shfl_xor(a4, 32);
    a5 += __shfl_xor(a5, 8); a5 += __shfl_xor(a5, 16); a5 += __shfl_xor(a5, 32);
    a6 += __shfl_xor(a6, 8); a6 += __shfl_xor(a6, 16); a6 += __shfl_xor(a6, 32);
    a7 += __shfl_xor(a7, 8); a7 += __shfl_xor(a7, 16); a7 += __shfl_xor(a7, 32);
    if (sub == 0) {
        float d = dinv[uw];
        uint4 o;
        o.x = (uint)f2bf(a0 * d) | ((uint)f2bf(a1 * d) << 16);
        o.y = (uint)f2bf(a2 * d) | ((uint)f2bf(a3 * d) << 16);
        o.z = (uint)f2bf(a4 * d) | ((uint)f2bf(a5 * d) << 16);
        o.w = (uint)f2bf(a6 * d) | ((uint)f2bf(a7 * d) << 16);
        *(uint4*)(out + ((size_t)uw << 6) + c) = o;
    }
}

// ---- T = (dinv*relu(Y*W1 + b1)) * Wct : two MFMA stages, LDS tile reuse ----
__global__ __launch_bounds__(256) void k_gemm_mfma(const ushort* __restrict__ Y,
                                                   const ushort* __restrict__ Wt,
                                                   const float* __restrict__ bias,
                                                   const float* __restrict__ dinv,
                                                   const ushort* __restrict__ Wct,
                                                   ushort* __restrict__ T, int n) {
    __shared__ __align__(16) ushort As[128][136];
    int tid = threadIdx.x;
    int r0 = blockIdx.x * 128;
#pragma unroll
    for (int i = 0; i < 8; i++) {
        int idx = tid + i * 256;
        int row = idx >> 4;
        int c8 = (idx & 15) * 8;
        int r = r0 + row;
        uint4 v = make_uint4(0u, 0u, 0u, 0u);
        if (r < n) v = *(const uint4*)(Y + (size_t)r * CH + c8);
        *(uint4*)&As[row][c8] = v;
    }
    __syncthreads();
    int w = tid >> 6, lane = tid & 63;
    int qm = lane & 15, quad = lane >> 4;
    floatx4 acc[2][8];
#pragma unroll
    for (int mi = 0; mi < 2; mi++)
#pragma unroll
        for (int nt = 0; nt < 8; nt++) acc[mi][nt] = (floatx4){0.f, 0.f, 0.f, 0.f};
#pragma unroll
    for (int ks = 0; ks < 4; ks++) {
        int k0 = ks * 32 + quad * 8;
        short8 va0 = *(const short8*)&As[w * 32 + qm][k0];
        short8 va1 = *(const short8*)&As[w * 32 + 16 + qm][k0];
#pragma unroll
        for (int nt = 0; nt < 8; nt++) {
            short8 b = *(const short8*)(Wt + (nt * 16 + qm) * CH + k0);
            acc[0][nt] = __builtin_amdgcn_mfma_f32_16x16x32_bf16(va0, b, acc[0][nt], 0, 0, 0);
            acc[1][nt] = __builtin_amdgcn_mfma_f32_16x16x32_bf16(va1, b, acc[1][nt], 0, 0, 0);
        }
    }
    // epilogue stage 1: hs = dinv*relu(acc+bias), write bf16 back to own rows
#pragma unroll
    for (int mi = 0; mi < 2; mi++) {
#pragma unroll
        for (int reg = 0; reg < 4; reg++) {
            int lrow = w * 32 + mi * 16 + quad * 4 + reg;
            int r = r0 + lrow;
            float d = (r < n) ? dinv[r] : 0.f;   // pad rows -> exact 0
#pragma unroll
            for (int nt = 0; nt < 8; nt++) {
                int cidx = nt * 16 + qm;
                float val = fmaxf(acc[mi][nt][reg] + bias[cidx], 0.f) * d;
                As[lrow][cidx] = f2bf(val);
            }
        }
    }
    __syncthreads();
    // stage 2: T tile = hs(128x128) * Wct(64x128)^T
    floatx4 acc2[2][4];
#pragma unroll
    for (int mi = 0; mi < 2; mi++)
#pragma unroll
        for (int nt = 0; nt < 4; nt++) acc2[mi][nt] = (floatx4){0.f, 0.f, 0.f, 0.f};
#pragma unroll
    for (int ks = 0; ks < 4; ks++) {
        int k0 = ks * 32 + quad * 8;
        short8 va0 = *(const short8*)&As[w * 32 + qm][k0];
        short8 va1 = *(const short8*)&As[w * 32 + 16 + qm][k0];
#pragma unroll
        for (int nt = 0; nt < 4; nt++) {
            short8 b = *(const short8*)(Wct + (nt * 16 + qm) * CH + k0);
            acc2[0][nt] = __builtin_amdgcn_mfma_f32_16x16x32_bf16(va0, b, acc2[0][nt], 0, 0, 0);
            acc2[1][nt] = __builtin_amdgcn_mfma_f32_16x16x32_bf16(va1, b, acc2[1][nt], 0, 0, 0);
        }
    }
#pragma unroll
    for (int mi = 0; mi < 2; mi++) {
#pragma unroll
        for (int reg = 0; reg < 4; reg++) {
            int r = r0 + w * 32 + mi * 16 + quad * 4 + reg;
            if (r >= n) continue;
#pragma unroll
            for (int nt = 0; nt < 4; nt++)
                T[(size_t)r * OC + nt * 16 + qm] = f2bf(acc2[mi][nt][reg]);
        }
    }
}

// ---- fused pool+out: one block per graph, binary-search node range,
// ---- block-reduce 64 channels, write out = mean + bc directly.
__global__ __launch_bounds__(256) void k_poolout(const ushort* __restrict__ Z,
                                                 const int* __restrict__ batch,
                                                 const float* __restrict__ bc,
                                                 float* __restrict__ out, int n) {
    __shared__ float red[4][OC];
    int g = blockIdx.x;
    // lower_bound(batch, g) and lower_bound(batch, g+1)
    int lo = 0, hi = n;
    while (lo < hi) { int m = (lo + hi) >> 1; if (batch[m] < g) lo = m + 1; else hi = m; }
    int beg = lo;
    hi = n;
    while (lo < hi) { int m = (lo + hi) >> 1; if (batch[m] < g + 1) lo = m + 1; else hi = m; }
    int end = lo;
    int w = threadIdx.x >> 6, lane = threadIdx.x & 63;
    float a = 0.f;
    for (int i = beg + w; i < end; i += 4)
        a += __uint_as_float(((uint)Z[(size_t)i * OC + lane]) << 16);
    red[w][lane] = a;
    __syncthreads();
    if (w == 0) {
        float s = red[0][lane] + red[1][lane] + red[2][lane] + red[3][lane];
        float invc = 1.f / fmaxf((float)(end - beg), 1.f);
        out[g * OC + lane] = s * invc + bc[lane];
    }
}

extern "C" void kernel_launch(void* const* d_in, const int* in_sizes, int n_in,
                              void* d_out, int out_size, void* d_ws, size_t ws_size,
                              hipStream_t stream) {
    const float* x   = (const float*)d_in[0];
    const float* W1  = (const float*)d_in[1];
    const float* b1  = (const float*)d_in[2];
    const float* W2  = (const float*)d_in[3];
    const float* b2  = (const float*)d_in[4];
    const float* Wfc = (const float*)d_in[5];
    const float* bfc = (const float*)d_in[6];
    const int* edges = (const int*)d_in[7];
    const int* batch = (const int*)d_in[8];

    const int n = in_sizes[8];        // 100000
    const int E = in_sizes[7] / 2;    // 1600000
    const int* esrc = edges;
    const int* edst = edges + E;

    const int NB = (n + 255) >> 8;            // 391 coarse buckets
    const int T = NB * NBLK;
    const int chunk = (E + NBLK - 1) / NBLK;

    char* p = (char*)d_ws;
    auto carve = [&](size_t bytes) {
        void* r = (void*)p;
        p += (bytes + 255) & ~(size_t)255;
        return r;
    };
    int*    bhT       = (int*)carve((size_t)T * 4);
    int*    off       = (int*)carve((size_t)T * 4);
    int*    bsums     = (int*)carve(512);
    int*    ebuf      = (int*)carve((size_t)E * 4);
    int2*   rowse     = (int2*)carve((size_t)n * 8);
    float*  dinv      = (float*)carve((size_t)n * 4);
    int*    ssrc      = (int*)carve(((size_t)E + (size_t)NB * PADSLACK + 256) * 4);
    int*    s32       = (int*)carve((size_t)n * 32 * 4);
    ushort* xb        = (ushort*)carve((size_t)(n + 1) * CH * 2);  // +sentinel row
    ushort* yb        = (ushort*)carve((size_t)n * CH * 2);
    ushort* tb        = (ushort*)carve((size_t)(n + 1) * OC * 2);  // +sentinel row
    ushort* Wt        = (ushort*)carve((size_t)CH * CH * 2);
    ushort* Wct       = (ushort*)carve((size_t)OC * CH * 2);
    float*  bc        = (float*)carve((size_t)OC * 4);

    int nScanBlocks = (T + 1023) / 1024;
    int cvtBlocks = (n * CH / 4 + 255) / 256;
    int prepBlocks = (CH * CH + CH * OC + OC + CH + OC + 255) / 256;

    // CSR build (atomic-free global ordering; rows = edges+self padded to x8)
    k_hist<<<NBLK, 256, 0, stream>>>(edst, bhT, E, NB, chunk);
    k_scan1<<<nScanBlocks, 256, 0, stream>>>(bhT, off, bsums, T);
    k_scan2<<<1, 128, 0, stream>>>(bsums, nScanBlocks);
    k_part<<<NBLK, 256, 0, stream>>>(esrc, edst, off, bsums, ebuf, E, NB, chunk);
    k_csr<<<NB, 256, 0, stream>>>(ebuf, off, bsums, rowse, dinv, ssrc, s32, n, NB, E);

    // fused features + weight prep (also zeroes sentinel rows of xb/tb)
    k_cvtprep<<<cvtBlocks + prepBlocks, 256, 0, stream>>>(
        x, dinv, xb, W1, W2, b2, Wfc, bfc, Wt, Wct, bc, tb, n, cvtBlocks);
    // y = dinv*(sum slots incl self)   (xb -> yb, 128 ch)
    k_agg<<<(n + 3) / 4, 256, 0, stream>>>(xb, rowse, ssrc, s32, dinv, yb, n);
    // t = (dinv*relu(y*W1 + b1)) * Wct   (yb -> tb, 64 ch)
    k_gemm_mfma<<<(n + 127) / 128, 256, 0, stream>>>(yb, Wt, b1, dinv, Wct, tb, n);
    // z = dinv*(sum slots incl self)   (tb -> xb-as-64ch)
    k_agg64<<<(n + 3) / 4, 256, 0, stream>>>(tb, rowse, ssrc, s32, dinv, xb, n);
    // out = mean-pool(z) + bc   (one block per graph, no atomics)
    k_poolout<<<NG, 256, 0, stream>>>(xb, batch, bc, (float*)d_out, n);
}